// Round 11
// baseline (587.799 us; speedup 1.0000x reference)
//
#include <hip/hip_runtime.h>
#include <stdint.h>

#define IN_F 4096
#define OUT_F 14336
#define QBLK 64

__device__ __constant__ float NF4_CODE_C[16] = {
    -1.0f, -0.6961928009986877f, -0.5250730514526367f, -0.39491748809814453f,
    -0.28444138169288635f, -0.18477343022823334f, -0.09105003625154495f, 0.0f,
    0.07958029955625534f, 0.16093020141124725f, 0.24611230194568634f,
    0.33791524171829224f, 0.44070982933044434f, 0.5626170039176941f,
    0.8333911895751953f, 1.0f};

typedef __attribute__((ext_vector_type(8))) short short8;   // 8 bf16 (4 VGPRs)
typedef __attribute__((ext_vector_type(4))) float f32x4;    // MFMA acc

__device__ __forceinline__ unsigned short f32_to_bf16_rne(float f) {
    union { float f; uint32_t u; } a; a.f = f;
    uint32_t u = a.u;
    uint32_t r = u + 0x7fffu + ((u >> 16) & 1u);
    return (unsigned short)(r >> 16);
}

// ---------------- Pass 1a: dequant W -> bf16 [N][K]
__global__ void dequant_w_kernel(const int* __restrict__ w,
                                 const float* __restrict__ absmax,
                                 unsigned short* __restrict__ W,
                                 long long n8) {
    long long i = (long long)blockIdx.x * blockDim.x + threadIdx.x;
    long long stride = (long long)gridDim.x * blockDim.x;
    for (; i < n8; i += stride) {
        const int4* p = (const int4*)(w + i * 8);
        int4 v0 = p[0], v1 = p[1];
        float s = absmax[i >> 3];
        union { unsigned short u[8]; float4 v; } out;
        out.u[0] = f32_to_bf16_rne(NF4_CODE_C[v0.x] * s);
        out.u[1] = f32_to_bf16_rne(NF4_CODE_C[v0.y] * s);
        out.u[2] = f32_to_bf16_rne(NF4_CODE_C[v0.z] * s);
        out.u[3] = f32_to_bf16_rne(NF4_CODE_C[v0.w] * s);
        out.u[4] = f32_to_bf16_rne(NF4_CODE_C[v1.x] * s);
        out.u[5] = f32_to_bf16_rne(NF4_CODE_C[v1.y] * s);
        out.u[6] = f32_to_bf16_rne(NF4_CODE_C[v1.z] * s);
        out.u[7] = f32_to_bf16_rne(NF4_CODE_C[v1.w] * s);
        *(float4*)(W + i * 8) = out.v;
    }
}

// ---------------- Pass 1b: x fp32 -> bf16
__global__ void cvt_x_kernel(const float* __restrict__ x,
                             unsigned short* __restrict__ xb,
                             long long n8) {
    long long i = (long long)blockIdx.x * blockDim.x + threadIdx.x;
    long long stride = (long long)gridDim.x * blockDim.x;
    for (; i < n8; i += stride) {
        const float4* p = (const float4*)(x + i * 8);
        float4 a = p[0], b = p[1];
        union { unsigned short u[8]; float4 v; } out;
        out.u[0] = f32_to_bf16_rne(a.x);
        out.u[1] = f32_to_bf16_rne(a.y);
        out.u[2] = f32_to_bf16_rne(a.z);
        out.u[3] = f32_to_bf16_rne(a.w);
        out.u[4] = f32_to_bf16_rne(b.x);
        out.u[5] = f32_to_bf16_rne(b.y);
        out.u[6] = f32_to_bf16_rne(b.z);
        out.u[7] = f32_to_bf16_rne(b.w);
        *(float4*)(xb + i * 8) = out.v;
    }
}

// ---------------- Pass 2: K-slab 2-phase pipelined bf16 GEMM (B^T)
// 256x256 tile, BK=64 = 2 k-slabs of 32; 2 LDS buffers (128 KiB); 8 waves
// (2M x 4N), wave tile 128x64. SYMMETRIC deadlines: every wave reads the
// SAME slab group per phase, so one VMW(8) per phase suffices and each
// staged group has 2 full phases (~1 tile) of landing slack.
// Phase = { 12 ds_read (slab frags) ; 4 gload_lds (one slab group, 3 groups
// ahead) ; 32 MFMA (setprio) ; VMW(8) ; BAR }.
// Ledger invariant: entering phA(t): outstanding = [slab1(t), slab0(t+1)];
//   phA(t): RD slab0(t); ST slab1(t+1) -> 12; VMW(8) forces slab1(t); BAR.
//   phB(t): RD slab1(t); ST slab0(t+2) -> 12; VMW(8) forces slab0(t+1); BAR.
// VMW precedes BAR (publish order, r4-proven). WAR: ST(slab s, t+2) targets
// the region whose last reads (phase of t) were consumed before that
// phase's BAR, which precedes this ST in every wave.
// Slab LDS geometry == r3's HW-proven BK=32 layout (64B rows, 4-slot XOR
// swizzle on both write-source and read): zero bank conflicts.
__device__ __forceinline__ void llds16(const unsigned short* g, unsigned short* l) {
    __builtin_amdgcn_global_load_lds(
        (const __attribute__((address_space(1))) unsigned int*)g,
        (__attribute__((address_space(3))) unsigned int*)l,
        16, 0, 0);
}

#define GK 4096
#define GN 14336

__global__ void __launch_bounds__(512, 2)
gemm_ks_bf16(const unsigned short* __restrict__ A,  // [M][4096] bf16 bits
             const unsigned short* __restrict__ B,  // [14336][4096] bf16 bits
             const float* __restrict__ bias,
             float* __restrict__ C, int Mtiles) {
    // buffer b at elem b*32768: A slab s at s*8192, B slab s at 16384+s*8192
    __shared__ unsigned short lds[65536];
    const int tid  = threadIdx.x;
    const int lane = tid & 63;
    const int wv   = tid >> 6;        // wave 0..7
    const int wr   = wv >> 2;         // M half
    const int wc   = wv & 3;          // N quarter

    // T1: bijective XCD swizzle (m204)
    const int nwg = gridDim.x;
    const int q = nwg >> 3, r = nwg & 7;
    const int xcd = blockIdx.x & 7, loc = blockIdx.x >> 3;
    const int s = (xcd < r ? xcd * (q + 1) : r * (q + 1) + (xcd - r) * q) + loc;
    const int tm = s % Mtiles;
    const int tn = s / Mtiles;
    const int brow = tm * 256;
    const int bcol = tn * 256;

    f32x4 acc[8][4] = {};

    // staging (r3-proven 64B-row geometry): thread T -> row T>>2 (half h adds
    // 128), LDS slot T&3 linear; global 16B-chunk pre-swizzled:
    // gch2 = (T&3) ^ g(row), g(row) = (row>>1)&3 = (T>>3)&3   [T2, rule #21]
    const int srow = tid >> 2;
    const int gch2 = ((tid & 3) ^ ((tid >> 3) & 3)) * 8;
    const unsigned short* pA = A + (size_t)(brow + srow) * GK + gch2;
    const unsigned short* pB = B + (size_t)(bcol + srow) * GK + gch2;

    // read offsets (r3-proven): slot = (lane>>4) ^ (((lane&15)>>1)&3)
    const int kqs4  = (((lane >> 4) ^ (((lane & 15) >> 1) & 3))) * 8;
    const int arow  = wr * 128 + (lane & 15);   // + i*16, rows 0..255
    const int brw   = wc * 64  + (lane & 15);   // + n*16

// stage one slab group (A+B, slab S of tile T, into buffer BUF): 4 loads
#define ST_SLAB(S, T, BUF) do {                                                 \
    llds16(pA + (size_t)(T) * 64 + (S) * 32,                                    \
           &lds[(BUF) + (S) * 8192 + wv * 512]);                                \
    llds16(pA + (size_t)128 * GK + (size_t)(T) * 64 + (S) * 32,                 \
           &lds[(BUF) + (S) * 8192 + 4096 + wv * 512]);                         \
    llds16(pB + (size_t)(T) * 64 + (S) * 32,                                    \
           &lds[(BUF) + 16384 + (S) * 8192 + wv * 512]);                        \
    llds16(pB + (size_t)128 * GK + (size_t)(T) * 64 + (S) * 32,                 \
           &lds[(BUF) + 16384 + (S) * 8192 + 4096 + wv * 512]);                 \
} while (0)

#define VMW(N) asm volatile("s_waitcnt vmcnt(" #N ")" ::: "memory")
#define BAR()  __builtin_amdgcn_s_barrier()

// one phase: read slab KK of buffer BUF, stage (STS,STT)->STBUF, 32 MFMA
#define PHASE(BUF, KK, STS, STT, STBUF, VN) do {                                \
    short8 af[8], bq[4];                                                        \
    _Pragma("unroll")                                                           \
    for (int i = 0; i < 8; ++i)                                                 \
        af[i] = *(const short8*)&lds[(BUF) + (KK) * 8192                        \
                                     + (arow + i * 16) * 32 + kqs4];            \
    _Pragma("unroll")                                                           \
    for (int n = 0; n < 4; ++n)                                                 \
        bq[n] = *(const short8*)&lds[(BUF) + 16384 + (KK) * 8192                \
                                     + (brw + n * 16) * 32 + kqs4];             \
    ST_SLAB(STS, STT, STBUF);                                                   \
    __builtin_amdgcn_s_setprio(1);                                              \
    _Pragma("unroll")                                                           \
    for (int i = 0; i < 8; ++i)                                                 \
        _Pragma("unroll")                                                       \
        for (int n = 0; n < 4; ++n)                                             \
            acc[i][n] = __builtin_amdgcn_mfma_f32_16x16x32_bf16(                \
                af[i], bq[n], acc[i][n], 0, 0, 0);                              \
    __builtin_amdgcn_s_setprio(0);                                              \
    VMW(VN); BAR();                                                             \
} while (0)

#define PHASE_NOST(BUF, KK, VN, DOVMW) do {                                     \
    short8 af[8], bq[4];                                                        \
    _Pragma("unroll")                                                           \
    for (int i = 0; i < 8; ++i)                                                 \
        af[i] = *(const short8*)&lds[(BUF) + (KK) * 8192                        \
                                     + (arow + i * 16) * 32 + kqs4];            \
    _Pragma("unroll")                                                           \
    for (int n = 0; n < 4; ++n)                                                 \
        bq[n] = *(const short8*)&lds[(BUF) + 16384 + (KK) * 8192                \
                                     + (brw + n * 16) * 32 + kqs4];             \
    __builtin_amdgcn_s_setprio(1);                                              \
    _Pragma("unroll")                                                           \
    for (int i = 0; i < 8; ++i)                                                 \
        _Pragma("unroll")                                                       \
        for (int n = 0; n < 4; ++n)                                             \
            acc[i][n] = __builtin_amdgcn_mfma_f32_16x16x32_bf16(                \
                af[i], bq[n], acc[i][n], 0, 0, 0);                              \
    __builtin_amdgcn_s_setprio(0);                                              \
    if (DOVMW) { VMW(VN); BAR(); }                                              \
} while (0)

    // prologue: slab0(0), slab1(0) -> buf0; slab0(1) -> buf1; force slab0(0)
    ST_SLAB(0, 0, 0);
    ST_SLAB(1, 0, 0);
    ST_SLAB(0, 1, 32768);
    VMW(8); BAR();

    // main loop: tile pairs (t even: buf0, t+1: buf1), t = 0..60
    #pragma unroll 1
    for (int t = 0; t < 62; t += 2) {
        PHASE(0,     0, 1, t + 1, 32768, 8);   // phA(t):   RD b0.s0, ST slab1(t+1)->buf1
        PHASE(0,     1, 0, t + 2, 0,     8);   // phB(t):   RD b0.s1, ST slab0(t+2)->buf0
        PHASE(32768, 0, 1, t + 2, 0,     8);   // phA(t+1): RD b1.s0, ST slab1(t+2)->buf0
        PHASE(32768, 1, 0, t + 3, 32768, 8);   // phB(t+1): RD b1.s1, ST slab0(t+3)->buf1
    }
    // tile 62 (buf0): stages slab1(63)->buf1, then drain
    PHASE(0, 0, 1, 63, 32768, 8);              // phA(62): forces slab1(62)
    PHASE_NOST(0, 1, 4, 1);                    // phB(62): forces slab0(63)
    PHASE_NOST(32768, 0, 0, 1);                // phA(63): forces slab1(63)
    PHASE_NOST(32768, 1, 0, 0);                // phB(63): no sync needed

#undef PHASE
#undef PHASE_NOST
#undef ST_SLAB
#undef VMW
#undef BAR

    // epilogue: D col = lane&15, row = (lane>>4)*4 + j  [verified layout]
    #pragma unroll
    for (int n = 0; n < 4; ++n) {
        const int col = bcol + wc * 64 + n * 16 + (lane & 15);
        const float bv = bias[col];
        #pragma unroll
        for (int i = 0; i < 8; ++i) {
            #pragma unroll
            for (int j = 0; j < 4; ++j) {
                const int row = brow + wr * 128 + i * 16 + (lane >> 4) * 4 + j;
                C[(size_t)row * GN + col] = acc[i][n][j] + bv;
            }
        }
    }
}

// ---------------- fallback: naive fused fp32
__global__ void naive_fused(const float* __restrict__ x, const int* __restrict__ w,
                            const float* __restrict__ am, const float* __restrict__ bias,
                            float* __restrict__ out, int M) {
    long long o = (long long)blockIdx.x * blockDim.x + threadIdx.x;
    if (o >= (long long)M * OUT_F) return;
    int m = (int)(o / OUT_F), n = (int)(o % OUT_F);
    const int* wr_ = w + (size_t)n * IN_F;
    const float* xr = x + (size_t)m * IN_F;
    const float* amr = am + (size_t)n * (IN_F / QBLK);
    float sum = 0.f;
    for (int k = 0; k < IN_F; ++k)
        sum += xr[k] * NF4_CODE_C[wr_[k]] * amr[k >> 6];
    out[o] = sum + bias[n];
}

extern "C" void kernel_launch(void* const* d_in, const int* in_sizes, int n_in,
                              void* d_out, int out_size, void* d_ws, size_t ws_size,
                              hipStream_t stream) {
    const float* x      = (const float*)d_in[0];
    const int*   w_idx  = (const int*)d_in[1];
    const float* absmax = (const float*)d_in[2];
    const float* bias   = (const float*)d_in[3];
    float* out = (float*)d_out;

    const int M = in_sizes[0] / IN_F;   // 4096
    const int N = OUT_F;                // 14336
    const int K = IN_F;                 // 4096

    const size_t needW = (size_t)N * K * 2;
    const size_t needX = (size_t)M * K * 2;
    if (ws_size >= needW + needX && (M % 256) == 0) {
        unsigned short* Wb = (unsigned short*)d_ws;
        unsigned short* Xb = (unsigned short*)((char*)d_ws + needW);

        long long n8w = (long long)N * K / 8;
        dequant_w_kernel<<<8192, 256, 0, stream>>>(w_idx, absmax, Wb, n8w);
        long long n8x = (long long)M * K / 8;
        cvt_x_kernel<<<4096, 256, 0, stream>>>(x, Xb, n8x);

        const int Mtiles = M / 256;
        dim3 grid(Mtiles * (N / 256));
        gemm_ks_bf16<<<grid, 512, 0, stream>>>(Xb, Wb, bias, out, Mtiles);
    } else {
        long long total = (long long)M * OUT_F;
        int blocks = (int)((total + 255) / 256);
        naive_fused<<<blocks, 256, 0, stream>>>(x, w_idx, absmax, bias, out, M);
    }
}

// Round 12
// 537.431 us; speedup vs baseline: 1.0937x; 1.0937x over previous
//
#include <hip/hip_runtime.h>
#include <stdint.h>

#define IN_F 4096
#define OUT_F 14336
#define QBLK 64

__device__ __constant__ float NF4_CODE_C[16] = {
    -1.0f, -0.6961928009986877f, -0.5250730514526367f, -0.39491748809814453f,
    -0.28444138169288635f, -0.18477343022823334f, -0.09105003625154495f, 0.0f,
    0.07958029955625534f, 0.16093020141124725f, 0.24611230194568634f,
    0.33791524171829224f, 0.44070982933044434f, 0.5626170039176941f,
    0.8333911895751953f, 1.0f};

typedef __attribute__((ext_vector_type(8))) short short8;   // 8 bf16 (4 VGPRs)
typedef __attribute__((ext_vector_type(4))) float f32x4;    // MFMA acc

__device__ __forceinline__ unsigned short f32_to_bf16_rne(float f) {
    union { float f; uint32_t u; } a; a.f = f;
    uint32_t u = a.u;
    uint32_t r = u + 0x7fffu + ((u >> 16) & 1u);
    return (unsigned short)(r >> 16);
}

// ---------------- Pass 1a: dequant W -> bf16 [N][K]
__global__ void dequant_w_kernel(const int* __restrict__ w,
                                 const float* __restrict__ absmax,
                                 unsigned short* __restrict__ W,
                                 long long n8) {
    long long i = (long long)blockIdx.x * blockDim.x + threadIdx.x;
    long long stride = (long long)gridDim.x * blockDim.x;
    for (; i < n8; i += stride) {
        const int4* p = (const int4*)(w + i * 8);
        int4 v0 = p[0], v1 = p[1];
        float s = absmax[i >> 3];
        union { unsigned short u[8]; float4 v; } out;
        out.u[0] = f32_to_bf16_rne(NF4_CODE_C[v0.x] * s);
        out.u[1] = f32_to_bf16_rne(NF4_CODE_C[v0.y] * s);
        out.u[2] = f32_to_bf16_rne(NF4_CODE_C[v0.z] * s);
        out.u[3] = f32_to_bf16_rne(NF4_CODE_C[v0.w] * s);
        out.u[4] = f32_to_bf16_rne(NF4_CODE_C[v1.x] * s);
        out.u[5] = f32_to_bf16_rne(NF4_CODE_C[v1.y] * s);
        out.u[6] = f32_to_bf16_rne(NF4_CODE_C[v1.z] * s);
        out.u[7] = f32_to_bf16_rne(NF4_CODE_C[v1.w] * s);
        *(float4*)(W + i * 8) = out.v;
    }
}

// ---------------- Pass 1b: x fp32 -> bf16
__global__ void cvt_x_kernel(const float* __restrict__ x,
                             unsigned short* __restrict__ xb,
                             long long n8) {
    long long i = (long long)blockIdx.x * blockDim.x + threadIdx.x;
    long long stride = (long long)gridDim.x * blockDim.x;
    for (; i < n8; i += stride) {
        const float4* p = (const float4*)(x + i * 8);
        float4 a = p[0], b = p[1];
        union { unsigned short u[8]; float4 v; } out;
        out.u[0] = f32_to_bf16_rne(a.x);
        out.u[1] = f32_to_bf16_rne(a.y);
        out.u[2] = f32_to_bf16_rne(a.z);
        out.u[3] = f32_to_bf16_rne(a.w);
        out.u[4] = f32_to_bf16_rne(b.x);
        out.u[5] = f32_to_bf16_rne(b.y);
        out.u[6] = f32_to_bf16_rne(b.z);
        out.u[7] = f32_to_bf16_rne(b.w);
        *(float4*)(xb + i * 8) = out.v;
    }
}

// ---------------- Pass 2: m201-style 8-phase bf16 GEMM (B^T).
// 256x256 tile, BK=64, 2 LDS buffers, 8 waves (2M x 4N), wave tile 128x64.
// Half-tiles (2 loads/wave each): HA0={STA0,STA2} (rows read by quadrant qm0
// of BOTH wr-groups), HA1={STA1,STA3}, HB0={STB00,STB10} (qn0 cols), HB1.
// Iter i computes tile 2i (quad order q00,q01,q10,q11) and 2i+1 (ROTATED:
// q10,q11,q00,q01). Phase = {reads; 1-half stage; BAR; setprio 16 MFMA;
// [VMW(4) at ph4/ph8]; BAR}. Stage slots: ph1:HA0(2i+1) ph2:HB1(2i+1)
// ph3:HA0(2i+2) ph4:HB0(2i+2)+VMW ph5:HA1(2i+2) ph6:HB1(2i+2) ph7:HA1(2i+3)
// ph8:HB0(2i+3)+VMW.
// Deadlines (all verified): ph1 reads HA0,HB0(2i) [staged ph3,4(i-1), forced
// ph8(i-1) VMW(4) which leaves only {HA1,HB0}(2i+1)]; ph2: HB1(2i) [ph6(i-1),
// forced ph8(i-1)]; ph3: HA1(2i) [ph5(i-1), forced ph8(i-1)]; ph5: HA1,HB0
// (2i+1) [ph7,8(i-1), forced ph4(i) VMW(4) which leaves {HA0,HB0}(2i+2)];
// ph6: HB1(2i+1) [ph2(i), forced ph4(i)]; ph7: HA0(2i+1) [ph1(i), forced
// ph4(i)]. WAR (all verified): every stage targets a region whose last read
// finished in the immediately preceding phase or earlier (rotated odd order
// makes HA1/HB1(2i) last-read at ph4, freeing ph5/ph6 slots, etc.).
// Outstanding never exceeds 12 loads/wave. Addressing identical to r3/r4
// (HW-proven: 0 bank conflicts, absmax 0.5).
__device__ __forceinline__ void llds16(const unsigned short* g, unsigned short* l) {
    __builtin_amdgcn_global_load_lds(
        (const __attribute__((address_space(1))) unsigned int*)g,
        (__attribute__((address_space(3))) unsigned int*)l,
        16, 0, 0);
}

#define GK 4096
#define GN 14336

__global__ void __launch_bounds__(512, 2)
gemm_8p_bf16(const unsigned short* __restrict__ A,  // [M][4096] bf16 bits
             const unsigned short* __restrict__ B,  // [14336][4096] bf16 bits
             const float* __restrict__ bias,
             float* __restrict__ C, int Mtiles) {
    __shared__ unsigned short lds[65536];
    const int tid  = threadIdx.x;
    const int lane = tid & 63;
    const int wv   = tid >> 6;        // wave 0..7
    const int wr   = wv >> 2;         // M half
    const int wc   = wv & 3;          // N quarter

    // T1: bijective XCD swizzle (m204)
    const int nwg = gridDim.x;
    const int q = nwg >> 3, r = nwg & 7;
    const int xcd = blockIdx.x & 7, loc = blockIdx.x >> 3;
    const int s = (xcd < r ? xcd * (q + 1) : r * (q + 1) + (xcd - r) * q) + loc;
    const int tm = s % Mtiles;
    const int tn = s / Mtiles;
    const int brow = tm * 256;
    const int bcol = tn * 256;

    f32x4 acc[8][4] = {};

    // staging (r3/r4-proven): lane l: row += l>>3, LDS slot l&7 linear,
    // global 16B-chunk pre-swizzled gch = (l&7)^((l>>3)&7)  [T2, rule #21]
    const int l8 = lane >> 3, l7 = lane & 7;
    const int gch = (l7 ^ (l8 & 7)) * 8;
    const unsigned short* pA = A + (size_t)(brow + wv * 8 + l8) * GK + gch;
    const unsigned short* pB = B + (size_t)(bcol + (wv >> 2) * 64 + (wv & 3) * 8 + l8) * GK + gch;
    const int ldsA = wv * 512;
    const int ldsB = 16384 + (wv >> 2) * 4096 + (wv & 3) * 512;

    // read offsets (r4-proven): slot = (kgrp + 4*kk) ^ (row&7)
    const int sl0 = (((lane >> 4)    ) ^ l7) * 8;
    const int sl1 = (((lane >> 4) + 4) ^ l7) * 8;
    const int ab = (wr * 128 + (lane & 15)) * 64;
    const int bb = 16384 + (wc * 64 + (lane & 15)) * 64;

#define ST_A(c, T, O)    llds16(pA + (size_t)(c) * 64 * GK + (size_t)(T) * 64, &lds[(O) + (c) * 4096 + ldsA])
#define ST_B(P, qq, T, O) llds16(pB + (size_t)((P) * 128 + (qq) * 32) * GK + (size_t)(T) * 64, &lds[(O) + (P) * 8192 + (qq) * 2048 + ldsB])

// half-tile stage groups
#define ST_HA0(T, O) do { ST_A(0, T, O); ST_A(2, T, O); } while (0)
#define ST_HA1(T, O) do { ST_A(1, T, O); ST_A(3, T, O); } while (0)
#define ST_HB0(T, O) do { ST_B(0, 0, T, O); ST_B(1, 0, T, O); } while (0)
#define ST_HB1(T, O) do { ST_B(0, 1, T, O); ST_B(1, 1, T, O); } while (0)

#define RD_A(af, qm, O) do { _Pragma("unroll")                                  \
    for (int rt = 0; rt < 4; ++rt) {                                            \
        af[rt][0] = *(const short8*)&lds[(O) + ab + (qm) * 4096 + rt * 1024 + sl0]; \
        af[rt][1] = *(const short8*)&lds[(O) + ab + (qm) * 4096 + rt * 1024 + sl1]; \
    } } while (0)
#define RD_B(bq, qn, O) do { _Pragma("unroll")                                  \
    for (int nt = 0; nt < 2; ++nt) {                                            \
        bq[nt][0] = *(const short8*)&lds[(O) + bb + (qn) * 2048 + nt * 1024 + sl0]; \
        bq[nt][1] = *(const short8*)&lds[(O) + bb + (qn) * 2048 + nt * 1024 + sl1]; \
    } } while (0)
#define MM(af, bq, i0, n0) do {                                                 \
    __builtin_amdgcn_s_setprio(1);                                              \
    _Pragma("unroll") for (int rt = 0; rt < 4; ++rt)                            \
    _Pragma("unroll") for (int nt = 0; nt < 2; ++nt)                            \
    _Pragma("unroll") for (int kk = 0; kk < 2; ++kk)                            \
        acc[(i0) + rt][(n0) + nt] = __builtin_amdgcn_mfma_f32_16x16x32_bf16(    \
            af[rt][kk], bq[nt][kk], acc[(i0) + rt][(n0) + nt], 0, 0, 0);        \
    __builtin_amdgcn_s_setprio(0);                                              \
} while (0)

#define VMW(N)   asm volatile("s_waitcnt vmcnt(" #N ")" ::: "memory")
#define BAR()    __builtin_amdgcn_s_barrier()
#define CFENCE() asm volatile("" ::: "memory")

#define B0O 0
#define B1O 32768

    short8 af0[4][2], af1[4][2], bq0[2][2], bq1[2][2];

    // prologue: tile 0 (all 4 halves) -> buf0; HA1(1), HB0(1) -> buf1;
    // VMW(4) leaves {HA1(1), HB0(1)} in flight, forces tile 0.
    ST_HA0(0, B0O); ST_HB0(0, B0O); ST_HA1(0, B0O); ST_HB1(0, B0O);
    ST_HA1(1, B1O); ST_HB0(1, B1O);
    VMW(4); BAR(); CFENCE();

    // main: iters i = 0..30, tiles 2i (buf0, even order), 2i+1 (buf1, rotated)
    #pragma unroll 1
    for (int i = 0; i < 31; ++i) {
        const int T1 = 2 * i + 1, T2 = 2 * i + 2, T3 = 2 * i + 3;
        // ph1: even tile q(0,0)
        RD_A(af0, 0, B0O); RD_B(bq0, 0, B0O);
        ST_HA0(T1, B1O);
        BAR(); CFENCE();
        MM(af0, bq0, 0, 0);
        BAR(); CFENCE();
        // ph2: q(0,1)
        RD_B(bq1, 1, B0O);
        ST_HB1(T1, B1O);
        BAR(); CFENCE();
        MM(af0, bq1, 0, 2);
        BAR(); CFENCE();
        // ph3: q(1,0)
        RD_A(af1, 1, B0O);
        ST_HA0(T2, B0O);
        BAR(); CFENCE();
        MM(af1, bq0, 4, 0);
        BAR(); CFENCE();
        // ph4: q(1,1); once-per-tile vmcnt
        ST_HB0(T2, B0O);
        BAR(); CFENCE();
        MM(af1, bq1, 4, 2);
        VMW(4); BAR(); CFENCE();
        // ph5: odd tile (rotated) q(1,0)
        RD_A(af1, 1, B1O); RD_B(bq0, 0, B1O);
        ST_HA1(T2, B0O);
        BAR(); CFENCE();
        MM(af1, bq0, 4, 0);
        BAR(); CFENCE();
        // ph6: q(1,1)
        RD_B(bq1, 1, B1O);
        ST_HB1(T2, B0O);
        BAR(); CFENCE();
        MM(af1, bq1, 4, 2);
        BAR(); CFENCE();
        // ph7: q(0,0)
        RD_A(af0, 0, B1O);
        ST_HA1(T3, B1O);
        BAR(); CFENCE();
        MM(af0, bq0, 0, 0);
        BAR(); CFENCE();
        // ph8: q(0,1); once-per-tile vmcnt
        ST_HB0(T3, B1O);
        BAR(); CFENCE();
        MM(af0, bq1, 0, 2);
        VMW(4); BAR(); CFENCE();
    }

    // tail iter: tiles 62 (buf0), 63 (buf1); stage only HA0(63), HB1(63)
    RD_A(af0, 0, B0O); RD_B(bq0, 0, B0O);
    ST_HA0(63, B1O);
    BAR(); CFENCE();
    MM(af0, bq0, 0, 0);
    BAR(); CFENCE();
    RD_B(bq1, 1, B0O);
    ST_HB1(63, B1O);
    BAR(); CFENCE();
    MM(af0, bq1, 0, 2);
    BAR(); CFENCE();
    RD_A(af1, 1, B0O);
    BAR(); CFENCE();
    MM(af1, bq0, 4, 0);
    BAR(); CFENCE();
    BAR(); CFENCE();
    MM(af1, bq1, 4, 2);
    VMW(0); BAR(); CFENCE();
    // tile 63 (rotated order)
    RD_A(af1, 1, B1O); RD_B(bq0, 0, B1O);
    BAR(); CFENCE();
    MM(af1, bq0, 4, 0);
    BAR(); CFENCE();
    RD_B(bq1, 1, B1O);
    BAR(); CFENCE();
    MM(af1, bq1, 4, 2);
    BAR(); CFENCE();
    RD_A(af0, 0, B1O);
    BAR(); CFENCE();
    MM(af0, bq0, 0, 0);
    MM(af0, bq1, 0, 2);

#undef VMW
#undef BAR
#undef CFENCE
#undef MM
#undef RD_A
#undef RD_B
#undef ST_HA0
#undef ST_HA1
#undef ST_HB0
#undef ST_HB1
#undef ST_A
#undef ST_B
#undef B0O
#undef B1O

    // epilogue: D col = lane&15, row = (lane>>4)*4 + j  [verified layout]
    #pragma unroll
    for (int n = 0; n < 4; ++n) {
        const int col = bcol + wc * 64 + n * 16 + (lane & 15);
        const float bv = bias[col];
        #pragma unroll
        for (int i = 0; i < 8; ++i) {
            #pragma unroll
            for (int j = 0; j < 4; ++j) {
                const int row = brow + wr * 128 + i * 16 + (lane >> 4) * 4 + j;
                C[(size_t)row * GN + col] = acc[i][n][j] + bv;
            }
        }
    }
}

// ---------------- fallback: naive fused fp32
__global__ void naive_fused(const float* __restrict__ x, const int* __restrict__ w,
                            const float* __restrict__ am, const float* __restrict__ bias,
                            float* __restrict__ out, int M) {
    long long o = (long long)blockIdx.x * blockDim.x + threadIdx.x;
    if (o >= (long long)M * OUT_F) return;
    int m = (int)(o / OUT_F), n = (int)(o % OUT_F);
    const int* wr_ = w + (size_t)n * IN_F;
    const float* xr = x + (size_t)m * IN_F;
    const float* amr = am + (size_t)n * (IN_F / QBLK);
    float sum = 0.f;
    for (int k = 0; k < IN_F; ++k)
        sum += xr[k] * NF4_CODE_C[wr_[k]] * amr[k >> 6];
    out[o] = sum + bias[n];
}

extern "C" void kernel_launch(void* const* d_in, const int* in_sizes, int n_in,
                              void* d_out, int out_size, void* d_ws, size_t ws_size,
                              hipStream_t stream) {
    const float* x      = (const float*)d_in[0];
    const int*   w_idx  = (const int*)d_in[1];
    const float* absmax = (const float*)d_in[2];
    const float* bias   = (const float*)d_in[3];
    float* out = (float*)d_out;

    const int M = in_sizes[0] / IN_F;   // 4096
    const int N = OUT_F;                // 14336
    const int K = IN_F;                 // 4096

    const size_t needW = (size_t)N * K * 2;
    const size_t needX = (size_t)M * K * 2;
    if (ws_size >= needW + needX && (M % 256) == 0) {
        unsigned short* Wb = (unsigned short*)d_ws;
        unsigned short* Xb = (unsigned short*)((char*)d_ws + needW);

        long long n8w = (long long)N * K / 8;
        dequant_w_kernel<<<8192, 256, 0, stream>>>(w_idx, absmax, Wb, n8w);
        long long n8x = (long long)M * K / 8;
        cvt_x_kernel<<<4096, 256, 0, stream>>>(x, Xb, n8x);

        const int Mtiles = M / 256;
        dim3 grid(Mtiles * (N / 256));
        gemm_8p_bf16<<<grid, 512, 0, stream>>>(Xb, Wb, bias, out, Mtiles);
    } else {
        long long total = (long long)M * OUT_F;
        int blocks = (int)((total + 255) / 256);
        naive_fused<<<blocks, 256, 0, stream>>>(x, w_idx, absmax, bias, out, M);
    }
}